// Round 8
// baseline (303.506 us; speedup 1.0000x reference)
//
#include <hip/hip_runtime.h>
#include <hip/hip_cooperative_groups.h>
#include <math.h>

namespace cg = cooperative_groups;

#define S 256
#define H 1024
#define NPAIR 32640  // S*(S-1)/2

// ---- workspace layout (float indices) ----
#define WS_T     0          // [8 kc][256 s][1024 c] score partials (8 MB)
#define WS_HP    2097152    // [8 kc][3 p][256 s][20 t] hw partials
#define WS_A     2220032    // [256]
#define WS_ZC    2220544    // [257]
#define WS_HW0   2220804    // [256*20]
#define WS_HW1   2225924    // [256*20]
#define WS_HW2   2231044    // [256*20]
#define WS_PW    2236164    // [257*20]
#define WS_LW    2241304    // [257*20] indexed by L=j-i+1
#define WS_LOSSP 2246444    // [128]
#define WS_RUN   2246700    // int[256]
#define WS_START 2246956    // int[256]
#define WS_END   2247212    // int[256]

__device__ __forceinline__ float tanh_fast(float x) {
    const float xc = fminf(fmaxf(x, -15.f), 15.f);
    const float ex = __expf(2.f * xc);
    return (ex - 1.f) / (ex + 1.f);
}

__global__ __launch_bounds__(256, 2) void fused(
        const float* __restrict__ hidden, const int* __restrict__ target,
        const float* __restrict__ w1, const float* __restrict__ b1,
        const float* __restrict__ w2, const float* __restrict__ b2,
        const float* __restrict__ lenemb, const float* __restrict__ fcw,
        const float* __restrict__ fcb, float* __restrict__ out,
        float* __restrict__ ws) {
    cg::grid_group grid = cg::this_grid();
    const int b = blockIdx.x, tid = threadIdx.x;

    // ================= P1: score partials (all 512 blocks) =================
    // kc = b>>6 (128-k chunk), rg = b&63 (4 rows). Thread: 4 cols (float4).
    // Per k: 1 broadcast ds_read_b128 + 1 coalesced float4 w-load + 16 FMA.
    {
        __shared__ __align__(16) float shH[128][4];
        const int kc = b >> 6, rg = b & 63;
        #pragma unroll
        for (int e = 0; e < 2; e++) {
            const int li = e * 256 + tid;
            const int kk = li & 127, r = li >> 7;
            shH[kk][r] = hidden[(rg * 4 + r) * H + kc * 128 + kk];
        }
        __syncthreads();
        float4 a0 = make_float4(0.f, 0.f, 0.f, 0.f), a1 = a0, a2 = a0, a3 = a0;
        const float* wp = w1 + (size_t)(kc * 128) * H + tid * 4;
        #pragma unroll 8
        for (int k = 0; k < 128; k++) {
            const float4 wv = *(const float4*)&wp[(size_t)k * H];
            const float4 h4 = *(const float4*)&shH[k][0];
            a0.x = fmaf(h4.x, wv.x, a0.x); a0.y = fmaf(h4.x, wv.y, a0.y);
            a0.z = fmaf(h4.x, wv.z, a0.z); a0.w = fmaf(h4.x, wv.w, a0.w);
            a1.x = fmaf(h4.y, wv.x, a1.x); a1.y = fmaf(h4.y, wv.y, a1.y);
            a1.z = fmaf(h4.y, wv.z, a1.z); a1.w = fmaf(h4.y, wv.w, a1.w);
            a2.x = fmaf(h4.z, wv.x, a2.x); a2.y = fmaf(h4.z, wv.y, a2.y);
            a2.z = fmaf(h4.z, wv.z, a2.z); a2.w = fmaf(h4.z, wv.w, a2.w);
            a3.x = fmaf(h4.w, wv.x, a3.x); a3.y = fmaf(h4.w, wv.y, a3.y);
            a3.z = fmaf(h4.w, wv.z, a3.z); a3.w = fmaf(h4.w, wv.w, a3.w);
        }
        float* op = ws + WS_T + (size_t)kc * (S * H) + (size_t)(rg * 4) * H + tid * 4;
        *(float4*)&op[0]     = a0;
        *(float4*)&op[H]     = a1;
        *(float4*)&op[2 * H] = a2;
        *(float4*)&op[3 * H] = a3;
    }
    grid.sync();

    // ===== P2: row reduce/tanh/dot (b<256) | hw partials (256..383) | lw (384,385) =====
    if (b < 256) {
        __shared__ float sred[256];
        const int c = tid * 4;
        float4 sum = make_float4(0.f, 0.f, 0.f, 0.f);
        #pragma unroll
        for (int kcz = 0; kcz < 8; kcz++) {
            const float4 tv = *(const float4*)&ws[WS_T + (size_t)kcz * (S * H) + (size_t)b * H + c];
            sum.x += tv.x; sum.y += tv.y; sum.z += tv.z; sum.w += tv.w;
        }
        const float4 b4 = *(const float4*)&b1[c];
        const float4 w4 = *(const float4*)&w2[c];
        float lacc = tanh_fast(sum.x + b4.x) * w4.x
                   + tanh_fast(sum.y + b4.y) * w4.y
                   + tanh_fast(sum.z + b4.z) * w4.z
                   + tanh_fast(sum.w + b4.w) * w4.w;
        sred[tid] = lacc;
        __syncthreads();
        for (int off = 128; off > 0; off >>= 1) {
            if (tid < off) sred[tid] += sred[tid + off];
            __syncthreads();
        }
        if (tid == 0) ws[WS_A + b] = sred[0];
    } else if (b < 384) {
        __shared__ __align__(16) float shHT[128][20];
        const int hb = b - 256;
        const int rg = hb & 15, kc = hb >> 4;
        {
            const int cc = tid & 127, rr = tid >> 7;
            #pragma unroll
            for (int e = 0; e < 8; e++) {
                const int r = e * 2 + rr;
                shHT[cc][r] = hidden[(rg * 16 + r) * H + kc * 128 + cc];
            }
        }
        __syncthreads();
        if (tid < 240) {
            const int t = tid % 20, g = tid / 20;   // g 0..11
            const int p = g >> 2, rsub = g & 3;
            const float* fw = fcw + (size_t)(p * H + kc * 128) * 20 + t;
            float a0 = 0.f, a1 = 0.f, a2 = 0.f, a3 = 0.f;
            #pragma unroll 8
            for (int k = 0; k < 128; k++) {
                const float w = fw[k * 20];
                const float4 h4 = *(const float4*)&shHT[k][rsub * 4];
                a0 = fmaf(h4.x, w, a0);
                a1 = fmaf(h4.y, w, a1);
                a2 = fmaf(h4.z, w, a2);
                a3 = fmaf(h4.w, w, a3);
            }
            float* hpo = ws + WS_HP + ((size_t)(kc * 3 + p) * 256 + rg * 16 + rsub * 4) * 20 + t;
            hpo[0] = a0; hpo[20] = a1; hpo[40] = a2; hpo[60] = a3;
        }
    } else if (b < 386) {
        for (int item = (b - 384) * 256 + tid; item < 5100; item += 512) {
            const int L2i = item / 20, t = item % 20;   // L = L2i + 2
            float v = 0.f;
            #pragma unroll
            for (int d = 0; d < 10; d++)
                v = fmaf(lenemb[(L2i + 2) * 10 + d], fcw[(3072 + d) * 20 + t], v);
            ws[WS_LW + (L2i + 2) * 20 + t] = v;
        }
    }
    grid.sync();

    // ===== P3: b0 = scans + hw0 reduce + Pw; b1/b2 = hw1/hw2 reduce =====
    if (b == 0) {
        __shared__ float shf[256], she[256];
        __shared__ int shi[256], shtg[256];
        __shared__ float soff[4][20];
        const int s = tid;

        for (int item = s; item < 5120; item += 256) {
            const int s2 = item / 20, t = item % 20;
            float v = 0.f;
            #pragma unroll
            for (int kcz = 0; kcz < 8; kcz++)
                v += ws[WS_HP + ((size_t)(kcz * 3) * 256 + s2) * 20 + t];
            ws[WS_HW0 + item] = v;
        }
        shtg[s] = target[s];
        const float a = ws[WS_A + s] + b2[0];
        shf[s] = a;
        __syncthreads();
        for (int off = 128; off > 0; off >>= 1) {
            if (s < off) shf[s] = fmaxf(shf[s], shf[s + off]);
            __syncthreads();
        }
        const float mx = shf[0];
        __syncthreads();
        const float ev = __expf(a - mx);
        she[s] = ev;
        shf[s] = ev;
        const int chg = (s == 0) ? 1 : (shtg[s] != shtg[s - 1]);
        shi[s] = chg;
        __syncthreads();
        for (int off = 1; off < 256; off <<= 1) {
            const float fv = (s >= off) ? shf[s - off] : 0.f;
            const int   iv = (s >= off) ? shi[s - off] : 0;
            __syncthreads();
            shf[s] += fv;
            shi[s] += iv;
            __syncthreads();
        }
        ws[WS_ZC + s + 1] = shf[s];
        if (s == 0) ws[WS_ZC] = 0.f;
        ((int*)ws)[WS_RUN + s]   = shi[s];
        ((int*)ws)[WS_START + s] = chg;
        ((int*)ws)[WS_END + s]   = (s == 255) ? 1 : (shtg[s] != shtg[s + 1]);
        __syncthreads();
        // Pw pass A: 80 lanes, seg-local cumsum written straight to ws
        if (s < 80) {
            const int t = s % 20, seg = s / 20;
            const int base = seg * 64;
            float pw = 0.f;
            for (int k = 0; k < 64; k++) {
                pw = fmaf(she[base + k], ws[WS_HW0 + (base + k) * 20 + t], pw);
                ws[WS_PW + (base + k + 1) * 20 + t] = pw;
            }
            soff[seg][t] = pw;
        }
        __syncthreads();
        if (s < 20) {
            const float T0 = soff[0][s], T1 = soff[1][s], T2 = soff[2][s];
            soff[1][s] = T0; soff[2][s] = T0 + T1; soff[3][s] = T0 + T1 + T2;
            ws[WS_PW + s] = 0.f;   // row 0
        }
        __syncthreads();
        for (int item = s; item < 3840; item += 256) {   // rows 65..256 fixup
            const int r = 65 + item / 20, t = item % 20;
            ws[WS_PW + r * 20 + t] += soff[(r - 1) >> 6][t];
        }
    } else if (b <= 2) {
        const int pidx = b;                       // 1 -> hw1, 2 -> hw2
        const int basew = (b == 1) ? WS_HW1 : WS_HW2;
        for (int item = tid; item < 5120; item += 256) {
            const int s2 = item / 20, t = item % 20;
            float v = 0.f;
            #pragma unroll
            for (int kcz = 0; kcz < 8; kcz++)
                v += ws[WS_HP + ((size_t)(kcz * 3 + pidx) * 256 + s2) * 20 + t];
            ws[basew + item] = v;
        }
    }
    grid.sync();

    // ===== P4: pairs (blocks 0..127, p = b*256+tid) =====
    if (b < 128) {
        __shared__ float sred4[256];
        const int p = b * 256 + tid;
        float lossacc = 0.f;
        if (p < NPAIR) {
            int i = (int)((511.0f - sqrtf((float)(261121 - 8 * p))) * 0.5f);
            while ((i + 1) * (510 - i) <= 2 * p) ++i;
            while (i > 0 && i * (511 - i) > 2 * p) --i;
            const int j = p - i * (511 - i) / 2 + i + 1;

            const float Zci  = ws[WS_ZC + i];
            const float invz = 1.f / (ws[WS_ZC + j + 1] - Zci);
            const int L = j - i + 1;
            const int* runid = (const int*)ws + WS_RUN;
            const int* stA   = (const int*)ws + WS_START;
            const int* enA   = (const int*)ws + WS_END;
            const int lbl = (runid[i] == runid[j] && stA[i] && enA[j]) ? target[j] : 0;

            const float4* pwj4 = (const float4*)(ws + WS_PW + (j + 1) * 20);
            const float4* pwi4 = (const float4*)(ws + WS_PW + i * 20);
            const float4* h14  = (const float4*)(ws + WS_HW1 + i * 20);
            const float4* h24  = (const float4*)(ws + WS_HW2 + j * 20);
            const float4* lw4  = (const float4*)(ws + WS_LW + L * 20);
            const float4* fb4  = (const float4*)fcb;
            float4* op4 = (float4*)(out + (size_t)p * 20);

            float lg[20];
            float mx = -1e30f, chosen = 0.f;
            #pragma unroll
            for (int q = 0; q < 5; q++) {
                const float4 aj = pwj4[q], ai = pwi4[q];
                const float4 bi = h14[q],  bj = h24[q];
                const float4 cl = lw4[q],  fb = fb4[q];
                float4 r;
                r.x = (aj.x - ai.x) * invz + bi.x + bj.x + cl.x + fb.x;
                r.y = (aj.y - ai.y) * invz + bi.y + bj.y + cl.y + fb.y;
                r.z = (aj.z - ai.z) * invz + bi.z + bj.z + cl.z + fb.z;
                r.w = (aj.w - ai.w) * invz + bi.w + bj.w + cl.w + fb.w;
                op4[q] = r;
                lg[q * 4 + 0] = r.x; lg[q * 4 + 1] = r.y;
                lg[q * 4 + 2] = r.z; lg[q * 4 + 3] = r.w;
                mx = fmaxf(mx, fmaxf(fmaxf(r.x, r.y), fmaxf(r.z, r.w)));
                chosen = (q * 4 + 0 == lbl) ? r.x : chosen;
                chosen = (q * 4 + 1 == lbl) ? r.y : chosen;
                chosen = (q * 4 + 2 == lbl) ? r.z : chosen;
                chosen = (q * 4 + 3 == lbl) ? r.w : chosen;
            }
            float se = 0.f;
            #pragma unroll
            for (int t = 0; t < 20; t++) se += __expf(lg[t] - mx);
            lossacc = -(chosen - mx - __logf(se));
        }
        sred4[tid] = lossacc;
        __syncthreads();
        for (int off = 128; off > 0; off >>= 1) {
            if (tid < off) sred4[tid] += sred4[tid + off];
            __syncthreads();
        }
        if (tid == 0) ws[WS_LOSSP + b] = sred4[0];
    }
    grid.sync();

    // ===== P5: loss reduce (block 0) =====
    if (b == 0) {
        __shared__ float sr2[128];
        if (tid < 128) sr2[tid] = ws[WS_LOSSP + tid];
        __syncthreads();
        for (int off = 64; off > 0; off >>= 1) {
            if (tid < off && tid + off < 128) sr2[tid] += sr2[tid + off];
            __syncthreads();
        }
        if (tid == 0) out[(size_t)NPAIR * 20] = sr2[0] / (float)NPAIR;
    }
}

extern "C" void kernel_launch(void* const* d_in, const int* in_sizes, int n_in,
                              void* d_out, int out_size, void* d_ws, size_t ws_size,
                              hipStream_t stream) {
    (void)in_sizes; (void)n_in; (void)out_size; (void)ws_size;
    const float* hidden = (const float*)d_in[0];
    const int*   target = (const int*)d_in[1];
    const float* w1     = (const float*)d_in[2];
    const float* b1     = (const float*)d_in[3];
    const float* w2     = (const float*)d_in[4];
    const float* b2     = (const float*)d_in[5];
    const float* lenemb = (const float*)d_in[6];
    const float* fcw    = (const float*)d_in[7];
    const float* fcb    = (const float*)d_in[8];
    float* out = (float*)d_out;
    float* ws  = (float*)d_ws;

    void* args[] = {(void*)&hidden, (void*)&target, (void*)&w1, (void*)&b1,
                    (void*)&w2, (void*)&b2, (void*)&lenemb, (void*)&fcw,
                    (void*)&fcb, (void*)&out, (void*)&ws};
    hipLaunchCooperativeKernel((const void*)fused, dim3(512), dim3(256),
                               args, 0, stream);
}

// Round 9
// 68.417 us; speedup vs baseline: 4.4361x; 4.4361x over previous
//
#include <hip/hip_runtime.h>
#include <math.h>

#define S 256
#define H 1024
#define NPAIR 32640  // S*(S-1)/2

// ---- workspace layout (float indices) ----
#define WS_T     0          // [8 kc][256 s][1024 c] score GEMM partials (8 MB)
#define WS_HP    2097152    // [8 kc][3 p][256 s][20 t] hw partials (480 KB)
#define WS_A     2220032    // [256]
#define WS_ZC    2220544    // [257]
#define WS_HW0   2220804    // [256*20]
#define WS_HW1   2225924    // [256*20]
#define WS_HW2   2231044    // [256*20]
#define WS_PW    2236164    // [257*20]
#define WS_LW    2241304    // [257*20] indexed by L=j-i+1
#define WS_LOSSP 2246444    // [255]
#define WS_RUN   2246700    // int[256]
#define WS_START 2246956    // int[256]
#define WS_END   2247212    // int[256]
#define WS_CTR   2247468    // int ticket for K2 (zeroed by K1)
#define WS_CTR2  2247469    // int ticket for K3 (zeroed by K1)

__device__ __forceinline__ float tanh_fast(float x) {
    const float xc = fminf(fmaxf(x, -15.f), 15.f);
    const float ex = __expf(2.f * xc);
    return (ex - 1.f) / (ex + 1.f);
}

// ============ K1: score partials (R7-P1 structure) + hw partials ============
// b<512:  score. kc=b>>6 (128-k chunk), rg=b&63 (4 rows). Thread: 4 cols.
//         Per k: 1 coalesced float4 w-load + 1 broadcast ds_read_b128 + 16 FMA.
// b>=512: hw partials (rg=hb&15, kc=hb>>4) — R3-verified path.
__global__ __launch_bounds__(256) void K1(const float* __restrict__ hidden,
                                          const float* __restrict__ w1,
                                          const float* __restrict__ fcw,
                                          float* __restrict__ ws) {
    const int tid = threadIdx.x;
    const int b = blockIdx.x;
    if (b == 0 && tid == 0) {
        ((int*)ws)[WS_CTR] = 0;
        ((int*)ws)[WS_CTR2] = 0;
    }

    if (b < 512) {
        __shared__ __align__(16) float shH[128][4];
        const int kc = b >> 6, rg = b & 63;
        #pragma unroll
        for (int e = 0; e < 2; e++) {
            const int li = e * 256 + tid;
            const int kk = li & 127, r = li >> 7;
            shH[kk][r] = hidden[(rg * 4 + r) * H + kc * 128 + kk];
        }
        __syncthreads();
        float4 a0 = make_float4(0.f, 0.f, 0.f, 0.f), a1 = a0, a2 = a0, a3 = a0;
        const float* wp = w1 + (size_t)(kc * 128) * H + tid * 4;
        #pragma unroll 8
        for (int k = 0; k < 128; k++) {
            const float4 wv = *(const float4*)&wp[(size_t)k * H];
            const float4 h4 = *(const float4*)&shH[k][0];
            a0.x = fmaf(h4.x, wv.x, a0.x); a0.y = fmaf(h4.x, wv.y, a0.y);
            a0.z = fmaf(h4.x, wv.z, a0.z); a0.w = fmaf(h4.x, wv.w, a0.w);
            a1.x = fmaf(h4.y, wv.x, a1.x); a1.y = fmaf(h4.y, wv.y, a1.y);
            a1.z = fmaf(h4.y, wv.z, a1.z); a1.w = fmaf(h4.y, wv.w, a1.w);
            a2.x = fmaf(h4.z, wv.x, a2.x); a2.y = fmaf(h4.z, wv.y, a2.y);
            a2.z = fmaf(h4.z, wv.z, a2.z); a2.w = fmaf(h4.z, wv.w, a2.w);
            a3.x = fmaf(h4.w, wv.x, a3.x); a3.y = fmaf(h4.w, wv.y, a3.y);
            a3.z = fmaf(h4.w, wv.z, a3.z); a3.w = fmaf(h4.w, wv.w, a3.w);
        }
        float* op = ws + WS_T + (size_t)kc * (S * H) + (size_t)(rg * 4) * H + tid * 4;
        *(float4*)&op[0]     = a0;
        *(float4*)&op[H]     = a1;
        *(float4*)&op[2 * H] = a2;
        *(float4*)&op[3 * H] = a3;
    } else {
        __shared__ __align__(16) float shHT[128][20];
        const int hb = b - 512;
        const int rg = hb & 15, kc = hb >> 4;
        {
            const int c = tid & 127, rr = tid >> 7;
            #pragma unroll
            for (int e = 0; e < 8; e++) {
                const int r = e * 2 + rr;
                shHT[c][r] = hidden[(rg * 16 + r) * H + kc * 128 + c];
            }
        }
        __syncthreads();
        if (tid < 240) {
            const int t = tid % 20, g = tid / 20;   // g 0..11
            const int p = g >> 2, rsub = g & 3;
            const float* fw = fcw + (size_t)(p * H + kc * 128) * 20 + t;
            float a0 = 0.f, a1 = 0.f, a2 = 0.f, a3 = 0.f;
            #pragma unroll 8
            for (int k = 0; k < 128; k++) {
                const float w = fw[k * 20];
                const float4 h4 = *(const float4*)&shHT[k][rsub * 4];
                a0 = fmaf(h4.x, w, a0);
                a1 = fmaf(h4.y, w, a1);
                a2 = fmaf(h4.z, w, a2);
                a3 = fmaf(h4.w, w, a3);
            }
            float* hpo = ws + WS_HP + ((size_t)(kc * 3 + p) * 256 + rg * 16 + rsub * 4) * 20 + t;
            hpo[0] = a0; hpo[20] = a1; hpo[40] = a2; hpo[60] = a3;
        }
    }
}

// ============ K2: slab reduce + tanh + w2 dot + hw reduce; last block: scans ============
__global__ __launch_bounds__(256) void K2(const float* __restrict__ b1,
                                          const float* __restrict__ w2,
                                          const float* __restrict__ b2,
                                          const int* __restrict__ target,
                                          const float* __restrict__ lenemb,
                                          const float* __restrict__ fcw,
                                          float* __restrict__ ws) {
    const int b = blockIdx.x, tid = threadIdx.x;
    __shared__ float sred[256];
    __shared__ int sticket;

    {
        const int c = tid * 4;
        float4 sum = make_float4(0.f, 0.f, 0.f, 0.f);
        #pragma unroll
        for (int kcz = 0; kcz < 8; kcz++) {
            const float4 tv = *(const float4*)&ws[WS_T + (size_t)kcz * (S * H) + (size_t)b * H + c];
            sum.x += tv.x; sum.y += tv.y; sum.z += tv.z; sum.w += tv.w;
        }
        const float4 b4 = *(const float4*)&b1[c];
        const float4 w4 = *(const float4*)&w2[c];
        sred[tid] = tanh_fast(sum.x + b4.x) * w4.x
                  + tanh_fast(sum.y + b4.y) * w4.y
                  + tanh_fast(sum.z + b4.z) * w4.z
                  + tanh_fast(sum.w + b4.w) * w4.w;
    }
    __syncthreads();
    for (int off = 128; off > 0; off >>= 1) {
        if (tid < off) sred[tid] += sred[tid + off];
        __syncthreads();
    }
    if (tid == 0) ws[WS_A + b] = sred[0];

    if (tid < 60) {
        const int t = tid % 20, p = tid / 20;
        float s = 0.f;
        #pragma unroll
        for (int kc = 0; kc < 8; kc++)
            s += ws[WS_HP + ((size_t)(kc * 3 + p) * 256 + b) * 20 + t];
        const int base = (p == 0) ? WS_HW0 : (p == 1) ? WS_HW1 : WS_HW2;
        ws[base + b * 20 + t] = s;
    }

    __threadfence();
    __syncthreads();
    if (tid == 0) sticket = atomicAdd((int*)ws + WS_CTR, 1);
    __syncthreads();
    if (sticket != 255) return;
    __threadfence();

    {
        const int s = tid;
        __shared__ float shf[256], she[256];
        __shared__ int shi[256], shtg[256];
        __shared__ float shlen[2550];
        __shared__ float shfct[200];
        __shared__ float shw0[5120];
        __shared__ float shpw[5120];
        __shared__ float soff[4][20];

        for (int idx = s; idx < 2550; idx += 256) shlen[idx] = lenemb[20 + idx];
        if (s < 200) shfct[s] = fcw[61440 + s];
        for (int idx = s; idx < 5120; idx += 256) shw0[idx] = ws[WS_HW0 + idx];

        shtg[s] = target[s];
        const float a = ws[WS_A + s] + b2[0];
        shf[s] = a;
        __syncthreads();

        for (int item = s; item < 5100; item += 256) {
            const int L2i = item / 20, t = item % 20;   // L = L2i + 2
            float v = 0.f;
            #pragma unroll
            for (int d = 0; d < 10; d++)
                v = fmaf(shlen[L2i * 10 + d], shfct[d * 20 + t], v);
            ws[WS_LW + (L2i + 2) * 20 + t] = v;
        }

        for (int off = 128; off > 0; off >>= 1) {
            if (s < off) shf[s] = fmaxf(shf[s], shf[s + off]);
            __syncthreads();
        }
        const float mx = shf[0];
        __syncthreads();
        const float ev = __expf(a - mx);
        she[s] = ev;
        shf[s] = ev;
        const int chg = (s == 0) ? 1 : (shtg[s] != shtg[s - 1]);
        shi[s] = chg;
        __syncthreads();
        for (int off = 1; off < 256; off <<= 1) {
            const float fv = (s >= off) ? shf[s - off] : 0.f;
            const int   iv = (s >= off) ? shi[s - off] : 0;
            __syncthreads();
            shf[s] += fv;
            shi[s] += iv;
            __syncthreads();
        }
        ws[WS_ZC + s + 1] = shf[s];
        if (s == 0) ws[WS_ZC] = 0.f;
        ((int*)ws)[WS_RUN + s]   = shi[s];
        ((int*)ws)[WS_START + s] = chg;
        ((int*)ws)[WS_END + s]   = (s == 255) ? 1 : (shtg[s] != shtg[s + 1]);

        if (s < 80) {
            const int t = s % 20, seg = s / 20;
            const int base = seg * 64;
            float pw = 0.f;
            for (int k = 0; k < 64; k++) {
                pw = fmaf(she[base + k], shw0[(base + k) * 20 + t], pw);
                shpw[(base + k) * 20 + t] = pw;
            }
        }
        __syncthreads();
        if (s < 20) {
            const float T0 = shpw[63 * 20 + s], T1 = shpw[127 * 20 + s], T2 = shpw[191 * 20 + s];
            soff[0][s] = 0.f; soff[1][s] = T0; soff[2][s] = T0 + T1; soff[3][s] = T0 + T1 + T2;
        }
        __syncthreads();
        for (int item = s; item < 5140; item += 256) {
            const int r = item / 20, t = item % 20;
            const float v = (r == 0) ? 0.f : shpw[(r - 1) * 20 + t] + soff[(r - 1) >> 6][t];
            ws[WS_PW + item] = v;
        }
    }
}

// ============ K3: pairs (255 x 128 = 32640) + last-block loss ============
__global__ __launch_bounds__(128) void K3(const int* __restrict__ target,
                                          const float* __restrict__ fcb,
                                          float* __restrict__ out,
                                          float* __restrict__ ws) {
    const int tid = threadIdx.x;
    const int p = blockIdx.x * 128 + tid;
    __shared__ float sred[128];
    __shared__ int sticket;
    float lossacc = 0.f;
    {
        int i = (int)((511.0f - sqrtf((float)(261121 - 8 * p))) * 0.5f);
        while ((i + 1) * (510 - i) <= 2 * p) ++i;
        while (i > 0 && i * (511 - i) > 2 * p) --i;
        const int j = p - i * (511 - i) / 2 + i + 1;

        const float Zci  = ws[WS_ZC + i];
        const float invz = 1.f / (ws[WS_ZC + j + 1] - Zci);
        const int L = j - i + 1;
        const int* runid = (const int*)ws + WS_RUN;
        const int* stA   = (const int*)ws + WS_START;
        const int* enA   = (const int*)ws + WS_END;
        const int lbl = (runid[i] == runid[j] && stA[i] && enA[j]) ? target[j] : 0;

        const float4* pwj4 = (const float4*)(ws + WS_PW + (j + 1) * 20);
        const float4* pwi4 = (const float4*)(ws + WS_PW + i * 20);
        const float4* h14  = (const float4*)(ws + WS_HW1 + i * 20);
        const float4* h24  = (const float4*)(ws + WS_HW2 + j * 20);
        const float4* lw4  = (const float4*)(ws + WS_LW + L * 20);
        const float4* fb4  = (const float4*)fcb;
        float4* op4 = (float4*)(out + (size_t)p * 20);

        float lg[20];
        float mx = -1e30f, chosen = 0.f;
        #pragma unroll
        for (int q = 0; q < 5; q++) {
            const float4 aj = pwj4[q], ai = pwi4[q];
            const float4 bi = h14[q],  bj = h24[q];
            const float4 cl = lw4[q],  fb = fb4[q];
            float4 r;
            r.x = (aj.x - ai.x) * invz + bi.x + bj.x + cl.x + fb.x;
            r.y = (aj.y - ai.y) * invz + bi.y + bj.y + cl.y + fb.y;
            r.z = (aj.z - ai.z) * invz + bi.z + bj.z + cl.z + fb.z;
            r.w = (aj.w - ai.w) * invz + bi.w + bj.w + cl.w + fb.w;
            op4[q] = r;
            lg[q * 4 + 0] = r.x; lg[q * 4 + 1] = r.y;
            lg[q * 4 + 2] = r.z; lg[q * 4 + 3] = r.w;
            mx = fmaxf(mx, fmaxf(fmaxf(r.x, r.y), fmaxf(r.z, r.w)));
            chosen = (q * 4 + 0 == lbl) ? r.x : chosen;
            chosen = (q * 4 + 1 == lbl) ? r.y : chosen;
            chosen = (q * 4 + 2 == lbl) ? r.z : chosen;
            chosen = (q * 4 + 3 == lbl) ? r.w : chosen;
        }
        float se = 0.f;
        #pragma unroll
        for (int t = 0; t < 20; t++) se += __expf(lg[t] - mx);
        lossacc = -(chosen - mx - __logf(se));
    }
    sred[tid] = lossacc;
    __syncthreads();
    for (int off = 64; off > 0; off >>= 1) {
        if (tid < off) sred[tid] += sred[tid + off];
        __syncthreads();
    }
    if (tid == 0) ws[WS_LOSSP + blockIdx.x] = sred[0];

    __threadfence();
    __syncthreads();
    if (tid == 0) sticket = atomicAdd((int*)ws + WS_CTR2, 1);
    __syncthreads();
    if (sticket != 254) return;
    __threadfence();
    sred[tid] = ws[WS_LOSSP + tid] + ((tid < 127) ? ws[WS_LOSSP + tid + 128] : 0.f);
    __syncthreads();
    for (int off = 64; off > 0; off >>= 1) {
        if (tid < off) sred[tid] += sred[tid + off];
        __syncthreads();
    }
    if (tid == 0) out[(size_t)NPAIR * 20] = sred[0] / (float)NPAIR;
}

extern "C" void kernel_launch(void* const* d_in, const int* in_sizes, int n_in,
                              void* d_out, int out_size, void* d_ws, size_t ws_size,
                              hipStream_t stream) {
    (void)in_sizes; (void)n_in; (void)out_size; (void)ws_size;
    const float* hidden = (const float*)d_in[0];
    const int*   target = (const int*)d_in[1];
    const float* w1     = (const float*)d_in[2];
    const float* b1     = (const float*)d_in[3];
    const float* w2     = (const float*)d_in[4];
    const float* b2     = (const float*)d_in[5];
    const float* lenemb = (const float*)d_in[6];
    const float* fcw    = (const float*)d_in[7];
    const float* fcb    = (const float*)d_in[8];
    float* out = (float*)d_out;
    float* ws  = (float*)d_ws;

    K1<<<640, 256, 0, stream>>>(hidden, w1, fcw, ws);
    K2<<<256, 256, 0, stream>>>(b1, w2, b2, target, lenemb, fcw, ws);
    K3<<<255, 128, 0, stream>>>(target, fcb, out, ws);
}

// Round 10
// 42.743 us; speedup vs baseline: 7.1007x; 1.6006x over previous
//
#include <hip/hip_runtime.h>
#include <math.h>

#define S 256
#define H 1024
#define NPAIR 32640  // S*(S-1)/2

// ---- workspace layout (float indices) ----
#define WS_T     0          // [8 kc][256 s][1024 c] score GEMM partials (8 MB)
#define WS_HP    2097152    // [8 kc][3 p][256 s][20 t] hw partials (480 KB)
#define WS_A     2220032    // [256]
#define WS_ZC    2220544    // [257]
#define WS_HW0   2220804    // [256*20]
#define WS_HW1   2225924    // [256*20]
#define WS_HW2   2231044    // [256*20]
#define WS_PW    2236164    // [257*20]
#define WS_LW    2241304    // [257*20] indexed by L=j-i+1
#define WS_LOSSP 2246444    // [128]
#define WS_RUN   2246700    // int[256]
#define WS_START 2246956    // int[256]
#define WS_END   2247212    // int[256]

__device__ __forceinline__ float tanh_fast(float x) {
    const float xc = fminf(fmaxf(x, -15.f), 15.f);
    const float ex = __expf(2.f * xc);
    return (ex - 1.f) / (ex + 1.f);
}

// ============ K1: score partials + hw partials (R9-measured <38us, est ~7) ============
// b<512:  score. kc=b>>6 (128-k chunk), rg=b&63 (4 rows). Thread: 4 cols.
//         Per k: 1 coalesced float4 w-load + 1 broadcast ds_read_b128 + 16 FMA.
// b>=512: hw partials (rg=hb&15, kc=hb>>4).
__global__ __launch_bounds__(256) void K1(const float* __restrict__ hidden,
                                          const float* __restrict__ w1,
                                          const float* __restrict__ fcw,
                                          float* __restrict__ ws) {
    const int tid = threadIdx.x;
    const int b = blockIdx.x;

    if (b < 512) {
        __shared__ __align__(16) float shH[128][4];
        const int kc = b >> 6, rg = b & 63;
        #pragma unroll
        for (int e = 0; e < 2; e++) {
            const int li = e * 256 + tid;
            const int kk = li & 127, r = li >> 7;
            shH[kk][r] = hidden[(rg * 4 + r) * H + kc * 128 + kk];
        }
        __syncthreads();
        float4 a0 = make_float4(0.f, 0.f, 0.f, 0.f), a1 = a0, a2 = a0, a3 = a0;
        const float* wp = w1 + (size_t)(kc * 128) * H + tid * 4;
        #pragma unroll 8
        for (int k = 0; k < 128; k++) {
            const float4 wv = *(const float4*)&wp[(size_t)k * H];
            const float4 h4 = *(const float4*)&shH[k][0];
            a0.x = fmaf(h4.x, wv.x, a0.x); a0.y = fmaf(h4.x, wv.y, a0.y);
            a0.z = fmaf(h4.x, wv.z, a0.z); a0.w = fmaf(h4.x, wv.w, a0.w);
            a1.x = fmaf(h4.y, wv.x, a1.x); a1.y = fmaf(h4.y, wv.y, a1.y);
            a1.z = fmaf(h4.y, wv.z, a1.z); a1.w = fmaf(h4.y, wv.w, a1.w);
            a2.x = fmaf(h4.z, wv.x, a2.x); a2.y = fmaf(h4.z, wv.y, a2.y);
            a2.z = fmaf(h4.z, wv.z, a2.z); a2.w = fmaf(h4.z, wv.w, a2.w);
            a3.x = fmaf(h4.w, wv.x, a3.x); a3.y = fmaf(h4.w, wv.y, a3.y);
            a3.z = fmaf(h4.w, wv.z, a3.z); a3.w = fmaf(h4.w, wv.w, a3.w);
        }
        float* op = ws + WS_T + (size_t)kc * (S * H) + (size_t)(rg * 4) * H + tid * 4;
        *(float4*)&op[0]     = a0;
        *(float4*)&op[H]     = a1;
        *(float4*)&op[2 * H] = a2;
        *(float4*)&op[3 * H] = a3;
    } else {
        __shared__ __align__(16) float shHT[128][20];
        const int hb = b - 512;
        const int rg = hb & 15, kc = hb >> 4;
        {
            const int c = tid & 127, rr = tid >> 7;
            #pragma unroll
            for (int e = 0; e < 8; e++) {
                const int r = e * 2 + rr;
                shHT[c][r] = hidden[(rg * 16 + r) * H + kc * 128 + c];
            }
        }
        __syncthreads();
        if (tid < 240) {
            const int t = tid % 20, g = tid / 20;   // g 0..11
            const int p = g >> 2, rsub = g & 3;
            const float* fw = fcw + (size_t)(p * H + kc * 128) * 20 + t;
            float a0 = 0.f, a1 = 0.f, a2 = 0.f, a3 = 0.f;
            #pragma unroll 8
            for (int k = 0; k < 128; k++) {
                const float w = fw[k * 20];
                const float4 h4 = *(const float4*)&shHT[k][rsub * 4];
                a0 = fmaf(h4.x, w, a0);
                a1 = fmaf(h4.y, w, a1);
                a2 = fmaf(h4.z, w, a2);
                a3 = fmaf(h4.w, w, a3);
            }
            float* hpo = ws + WS_HP + ((size_t)(kc * 3 + p) * 256 + rg * 16 + rsub * 4) * 20 + t;
            hpo[0] = a0; hpo[20] = a1; hpo[40] = a2; hpo[60] = a3;
        }
    }
}

// ============ K2: per-row slab reduce + tanh + w2 dot + hw reduce (no sync) ============
__global__ __launch_bounds__(256) void K2(const float* __restrict__ b1,
                                          const float* __restrict__ w2,
                                          float* __restrict__ ws) {
    const int b = blockIdx.x, tid = threadIdx.x;
    __shared__ float sred[256];
    {
        const int c = tid * 4;
        float4 sum = make_float4(0.f, 0.f, 0.f, 0.f);
        #pragma unroll
        for (int kcz = 0; kcz < 8; kcz++) {
            const float4 tv = *(const float4*)&ws[WS_T + (size_t)kcz * (S * H) + (size_t)b * H + c];
            sum.x += tv.x; sum.y += tv.y; sum.z += tv.z; sum.w += tv.w;
        }
        const float4 b4 = *(const float4*)&b1[c];
        const float4 w4 = *(const float4*)&w2[c];
        sred[tid] = tanh_fast(sum.x + b4.x) * w4.x
                  + tanh_fast(sum.y + b4.y) * w4.y
                  + tanh_fast(sum.z + b4.z) * w4.z
                  + tanh_fast(sum.w + b4.w) * w4.w;
    }
    __syncthreads();
    for (int off = 128; off > 0; off >>= 1) {
        if (tid < off) sred[tid] += sred[tid + off];
        __syncthreads();
    }
    if (tid == 0) ws[WS_A + b] = sred[0];

    if (tid < 60) {
        const int t = tid % 20, p = tid / 20;
        float s = 0.f;
        #pragma unroll
        for (int kc = 0; kc < 8; kc++)
            s += ws[WS_HP + ((size_t)(kc * 3 + p) * 256 + b) * 20 + t];
        const int base = (p == 0) ? WS_HW0 : (p == 1) ? WS_HW1 : WS_HW2;
        ws[base + b * 20 + t] = s;
    }
}

// ============ K3: 1 block — lw table, max/e, scans, Pw (R3/R4-verified) ============
__global__ __launch_bounds__(256) void K3(const float* __restrict__ b2,
                                          const int* __restrict__ target,
                                          const float* __restrict__ lenemb,
                                          const float* __restrict__ fcw,
                                          float* __restrict__ ws) {
    const int s = threadIdx.x;
    __shared__ float shf[256], she[256];
    __shared__ int shi[256], shtg[256];
    __shared__ float shlen[2550];
    __shared__ float shfct[200];
    __shared__ float shw0[5120];
    __shared__ float shpw[5120];
    __shared__ float soff[4][20];

    for (int idx = s; idx < 2550; idx += 256) shlen[idx] = lenemb[20 + idx];
    if (s < 200) shfct[s] = fcw[61440 + s];
    for (int idx = s; idx < 5120; idx += 256) shw0[idx] = ws[WS_HW0 + idx];

    shtg[s] = target[s];
    const float a = ws[WS_A + s] + b2[0];
    shf[s] = a;
    __syncthreads();

    for (int item = s; item < 5100; item += 256) {
        const int L2i = item / 20, t = item % 20;   // L = L2i + 2
        float v = 0.f;
        #pragma unroll
        for (int d = 0; d < 10; d++)
            v = fmaf(shlen[L2i * 10 + d], shfct[d * 20 + t], v);
        ws[WS_LW + (L2i + 2) * 20 + t] = v;
    }

    for (int off = 128; off > 0; off >>= 1) {
        if (s < off) shf[s] = fmaxf(shf[s], shf[s + off]);
        __syncthreads();
    }
    const float mx = shf[0];
    __syncthreads();
    const float ev = __expf(a - mx);
    she[s] = ev;
    shf[s] = ev;
    const int chg = (s == 0) ? 1 : (shtg[s] != shtg[s - 1]);
    shi[s] = chg;
    __syncthreads();
    for (int off = 1; off < 256; off <<= 1) {
        const float fv = (s >= off) ? shf[s - off] : 0.f;
        const int   iv = (s >= off) ? shi[s - off] : 0;
        __syncthreads();
        shf[s] += fv;
        shi[s] += iv;
        __syncthreads();
    }
    ws[WS_ZC + s + 1] = shf[s];
    if (s == 0) ws[WS_ZC] = 0.f;
    ((int*)ws)[WS_RUN + s]   = shi[s];
    ((int*)ws)[WS_START + s] = chg;
    ((int*)ws)[WS_END + s]   = (s == 255) ? 1 : (shtg[s] != shtg[s + 1]);

    if (s < 80) {
        const int t = s % 20, seg = s / 20;
        const int base = seg * 64;
        float pw = 0.f;
        for (int k = 0; k < 64; k++) {
            pw = fmaf(she[base + k], shw0[(base + k) * 20 + t], pw);
            shpw[(base + k) * 20 + t] = pw;
        }
    }
    __syncthreads();
    if (s < 20) {
        const float T0 = shpw[63 * 20 + s], T1 = shpw[127 * 20 + s], T2 = shpw[191 * 20 + s];
        soff[0][s] = 0.f; soff[1][s] = T0; soff[2][s] = T0 + T1; soff[3][s] = T0 + T1 + T2;
    }
    __syncthreads();
    for (int item = s; item < 5140; item += 256) {
        const int r = item / 20, t = item % 20;
        const float v = (r == 0) ? 0.f : shpw[(r - 1) * 20 + t] + soff[(r - 1) >> 6][t];
        ws[WS_PW + item] = v;
    }
}

// ============ K4: pairs (128 blocks x 256, no ticket) ============
__global__ __launch_bounds__(256) void K4(const int* __restrict__ target,
                                          const float* __restrict__ fcb,
                                          float* __restrict__ out,
                                          float* __restrict__ ws) {
    const int tid = threadIdx.x;
    const int p = blockIdx.x * 256 + tid;
    __shared__ float sred[256];
    float lossacc = 0.f;
    if (p < NPAIR) {
        int i = (int)((511.0f - sqrtf((float)(261121 - 8 * p))) * 0.5f);
        while ((i + 1) * (510 - i) <= 2 * p) ++i;
        while (i > 0 && i * (511 - i) > 2 * p) --i;
        const int j = p - i * (511 - i) / 2 + i + 1;

        const float Zci  = ws[WS_ZC + i];
        const float invz = 1.f / (ws[WS_ZC + j + 1] - Zci);
        const int L = j - i + 1;
        const int* runid = (const int*)ws + WS_RUN;
        const int* stA   = (const int*)ws + WS_START;
        const int* enA   = (const int*)ws + WS_END;
        const int lbl = (runid[i] == runid[j] && stA[i] && enA[j]) ? target[j] : 0;

        const float4* pwj4 = (const float4*)(ws + WS_PW + (j + 1) * 20);
        const float4* pwi4 = (const float4*)(ws + WS_PW + i * 20);
        const float4* h14  = (const float4*)(ws + WS_HW1 + i * 20);
        const float4* h24  = (const float4*)(ws + WS_HW2 + j * 20);
        const float4* lw4  = (const float4*)(ws + WS_LW + L * 20);
        const float4* fb4  = (const float4*)fcb;
        float4* op4 = (float4*)(out + (size_t)p * 20);

        float lg[20];
        float mx = -1e30f, chosen = 0.f;
        #pragma unroll
        for (int q = 0; q < 5; q++) {
            const float4 aj = pwj4[q], ai = pwi4[q];
            const float4 bi = h14[q],  bj = h24[q];
            const float4 cl = lw4[q],  fb = fb4[q];
            float4 r;
            r.x = (aj.x - ai.x) * invz + bi.x + bj.x + cl.x + fb.x;
            r.y = (aj.y - ai.y) * invz + bi.y + bj.y + cl.y + fb.y;
            r.z = (aj.z - ai.z) * invz + bi.z + bj.z + cl.z + fb.z;
            r.w = (aj.w - ai.w) * invz + bi.w + bj.w + cl.w + fb.w;
            op4[q] = r;
            lg[q * 4 + 0] = r.x; lg[q * 4 + 1] = r.y;
            lg[q * 4 + 2] = r.z; lg[q * 4 + 3] = r.w;
            mx = fmaxf(mx, fmaxf(fmaxf(r.x, r.y), fmaxf(r.z, r.w)));
            chosen = (q * 4 + 0 == lbl) ? r.x : chosen;
            chosen = (q * 4 + 1 == lbl) ? r.y : chosen;
            chosen = (q * 4 + 2 == lbl) ? r.z : chosen;
            chosen = (q * 4 + 3 == lbl) ? r.w : chosen;
        }
        float se = 0.f;
        #pragma unroll
        for (int t = 0; t < 20; t++) se += __expf(lg[t] - mx);
        lossacc = -(chosen - mx - __logf(se));
    }
    sred[tid] = lossacc;
    __syncthreads();
    for (int off = 128; off > 0; off >>= 1) {
        if (tid < off) sred[tid] += sred[tid + off];
        __syncthreads();
    }
    if (tid == 0) ws[WS_LOSSP + blockIdx.x] = sred[0];
}

// ============ K5: final loss reduce (1 block) ============
__global__ __launch_bounds__(128) void K5(float* __restrict__ out,
                                          float* __restrict__ ws) {
    __shared__ float sh[128];
    const int t = threadIdx.x;
    sh[t] = ws[WS_LOSSP + t];
    __syncthreads();
    for (int off = 64; off > 0; off >>= 1) {
        if (t < off) sh[t] += sh[t + off];
        __syncthreads();
    }
    if (t == 0) out[(size_t)NPAIR * 20] = sh[0] / (float)NPAIR;
}

extern "C" void kernel_launch(void* const* d_in, const int* in_sizes, int n_in,
                              void* d_out, int out_size, void* d_ws, size_t ws_size,
                              hipStream_t stream) {
    (void)in_sizes; (void)n_in; (void)out_size; (void)ws_size;
    const float* hidden = (const float*)d_in[0];
    const int*   target = (const int*)d_in[1];
    const float* w1     = (const float*)d_in[2];
    const float* b1     = (const float*)d_in[3];
    const float* w2     = (const float*)d_in[4];
    const float* b2     = (const float*)d_in[5];
    const float* lenemb = (const float*)d_in[6];
    const float* fcw    = (const float*)d_in[7];
    const float* fcb    = (const float*)d_in[8];
    float* out = (float*)d_out;
    float* ws  = (float*)d_ws;

    K1<<<640, 256, 0, stream>>>(hidden, w1, fcw, ws);
    K2<<<256, 256, 0, stream>>>(b1, w2, ws);
    K3<<<1, 256, 0, stream>>>(b2, target, lenemb, fcw, ws);
    K4<<<128, 256, 0, stream>>>(target, fcb, out, ws);
    K5<<<1, 128, 0, stream>>>(out, ws);
}

// Round 11
// 37.201 us; speedup vs baseline: 8.1585x; 1.1490x over previous
//
#include <hip/hip_runtime.h>
#include <math.h>

#define S 256
#define H 1024
#define NPAIR 32640  // S*(S-1)/2

// ---- workspace layout (float indices) ----
#define WS_T     0          // [8 kc][256 s][1024 c] score GEMM partials (8 MB)
#define WS_HP    2097152    // [8 kc][3 p][256 s][20 t] hw partials (480 KB)
#define WS_A     2220032    // [256]
#define WS_HW0   2220804    // [256*20]
#define WS_HW1   2225924    // [256*20]
#define WS_HW2   2231044    // [256*20]
#define WS_LW    2241304    // [257*20] indexed by L=j-i+1
#define WS_LOSSP 2246444    // [255]

__device__ __forceinline__ float tanh_fast(float x) {
    const float xc = fminf(fmaxf(x, -15.f), 15.f);
    const float ex = __expf(2.f * xc);
    return (ex - 1.f) / (ex + 1.f);
}

// ============ K1: score partials + hw partials (R10-verified) ============
__global__ __launch_bounds__(256) void K1(const float* __restrict__ hidden,
                                          const float* __restrict__ w1,
                                          const float* __restrict__ fcw,
                                          float* __restrict__ ws) {
    const int tid = threadIdx.x;
    const int b = blockIdx.x;

    if (b < 512) {
        __shared__ __align__(16) float shH[128][4];
        const int kc = b >> 6, rg = b & 63;
        #pragma unroll
        for (int e = 0; e < 2; e++) {
            const int li = e * 256 + tid;
            const int kk = li & 127, r = li >> 7;
            shH[kk][r] = hidden[(rg * 4 + r) * H + kc * 128 + kk];
        }
        __syncthreads();
        float4 a0 = make_float4(0.f, 0.f, 0.f, 0.f), a1 = a0, a2 = a0, a3 = a0;
        const float* wp = w1 + (size_t)(kc * 128) * H + tid * 4;
        #pragma unroll 8
        for (int k = 0; k < 128; k++) {
            const float4 wv = *(const float4*)&wp[(size_t)k * H];
            const float4 h4 = *(const float4*)&shH[k][0];
            a0.x = fmaf(h4.x, wv.x, a0.x); a0.y = fmaf(h4.x, wv.y, a0.y);
            a0.z = fmaf(h4.x, wv.z, a0.z); a0.w = fmaf(h4.x, wv.w, a0.w);
            a1.x = fmaf(h4.y, wv.x, a1.x); a1.y = fmaf(h4.y, wv.y, a1.y);
            a1.z = fmaf(h4.y, wv.z, a1.z); a1.w = fmaf(h4.y, wv.w, a1.w);
            a2.x = fmaf(h4.z, wv.x, a2.x); a2.y = fmaf(h4.z, wv.y, a2.y);
            a2.z = fmaf(h4.z, wv.z, a2.z); a2.w = fmaf(h4.z, wv.w, a2.w);
            a3.x = fmaf(h4.w, wv.x, a3.x); a3.y = fmaf(h4.w, wv.y, a3.y);
            a3.z = fmaf(h4.w, wv.z, a3.z); a3.w = fmaf(h4.w, wv.w, a3.w);
        }
        float* op = ws + WS_T + (size_t)kc * (S * H) + (size_t)(rg * 4) * H + tid * 4;
        *(float4*)&op[0]     = a0;
        *(float4*)&op[H]     = a1;
        *(float4*)&op[2 * H] = a2;
        *(float4*)&op[3 * H] = a3;
    } else {
        __shared__ __align__(16) float shHT[128][20];
        const int hb = b - 512;
        const int rg = hb & 15, kc = hb >> 4;
        {
            const int c = tid & 127, rr = tid >> 7;
            #pragma unroll
            for (int e = 0; e < 8; e++) {
                const int r = e * 2 + rr;
                shHT[c][r] = hidden[(rg * 16 + r) * H + kc * 128 + c];
            }
        }
        __syncthreads();
        if (tid < 240) {
            const int t = tid % 20, g = tid / 20;   // g 0..11
            const int p = g >> 2, rsub = g & 3;
            const float* fw = fcw + (size_t)(p * H + kc * 128) * 20 + t;
            float a0 = 0.f, a1 = 0.f, a2 = 0.f, a3 = 0.f;
            #pragma unroll 8
            for (int k = 0; k < 128; k++) {
                const float w = fw[k * 20];
                const float4 h4 = *(const float4*)&shHT[k][rsub * 4];
                a0 = fmaf(h4.x, w, a0);
                a1 = fmaf(h4.y, w, a1);
                a2 = fmaf(h4.z, w, a2);
                a3 = fmaf(h4.w, w, a3);
            }
            float* hpo = ws + WS_HP + ((size_t)(kc * 3 + p) * 256 + rg * 16 + rsub * 4) * 20 + t;
            hpo[0] = a0; hpo[20] = a1; hpo[40] = a2; hpo[60] = a3;
        }
    }
}

// ============ K2: row reduce + tanh + w2 dot + hw reduce; block 0 also lw ============
__global__ __launch_bounds__(256) void K2(const float* __restrict__ b1,
                                          const float* __restrict__ w2,
                                          const float* __restrict__ lenemb,
                                          const float* __restrict__ fcw,
                                          float* __restrict__ ws) {
    const int b = blockIdx.x, tid = threadIdx.x;
    __shared__ float sred[256];
    {
        const int c = tid * 4;
        float4 sum = make_float4(0.f, 0.f, 0.f, 0.f);
        #pragma unroll
        for (int kcz = 0; kcz < 8; kcz++) {
            const float4 tv = *(const float4*)&ws[WS_T + (size_t)kcz * (S * H) + (size_t)b * H + c];
            sum.x += tv.x; sum.y += tv.y; sum.z += tv.z; sum.w += tv.w;
        }
        const float4 b4 = *(const float4*)&b1[c];
        const float4 w4 = *(const float4*)&w2[c];
        sred[tid] = tanh_fast(sum.x + b4.x) * w4.x
                  + tanh_fast(sum.y + b4.y) * w4.y
                  + tanh_fast(sum.z + b4.z) * w4.z
                  + tanh_fast(sum.w + b4.w) * w4.w;
    }
    __syncthreads();
    for (int off = 128; off > 0; off >>= 1) {
        if (tid < off) sred[tid] += sred[tid + off];
        __syncthreads();
    }
    if (tid == 0) ws[WS_A + b] = sred[0];

    if (tid < 60) {
        const int t = tid % 20, p = tid / 20;
        float s = 0.f;
        #pragma unroll
        for (int kc = 0; kc < 8; kc++)
            s += ws[WS_HP + ((size_t)(kc * 3 + p) * 256 + b) * 20 + t];
        const int base = (p == 0) ? WS_HW0 : (p == 1) ? WS_HW1 : WS_HW2;
        ws[base + b * 20 + t] = s;
    }

    if (b == 0) {   // lw table: L=2..256
        for (int item = tid; item < 5100; item += 256) {
            const int L2i = item / 20, t = item % 20;
            float v = 0.f;
            #pragma unroll
            for (int d = 0; d < 10; d++)
                v = fmaf(lenemb[(L2i + 2) * 10 + d], fcw[(3072 + d) * 20 + t], v);
            ws[WS_LW + (L2i + 2) * 20 + t] = v;
        }
    }
}

// ============ K3: pair rows with replicated scan prologue ============
// Block i (0..254); thread j. Prologue: recompute ZC/runid/Pw from A,HW0 in LDS.
__global__ __launch_bounds__(256) void K3(const int* __restrict__ target,
                                          const float* __restrict__ b2,
                                          const float* __restrict__ fcb,
                                          float* __restrict__ out,
                                          float* __restrict__ ws) {
    const int i = blockIdx.x;
    const int j = threadIdx.x;
    const int s = j;
    __shared__ float shf[256], she[256];
    __shared__ int shi[256], shtg[256];
    __shared__ float shw0[5120];
    __shared__ float shpw[5120];
    __shared__ float soff[4][20];
    __shared__ float sPwi[20], shw1i[20], sfcb[20];
    __shared__ float sred[256];

    for (int idx = s; idx < 5120; idx += 256) shw0[idx] = ws[WS_HW0 + idx];
    shtg[s] = target[s];
    const float a = ws[WS_A + s] + b2[0];
    sred[s] = a;
    __syncthreads();
    for (int off = 128; off > 0; off >>= 1) {
        if (s < off) sred[s] = fmaxf(sred[s], sred[s + off]);
        __syncthreads();
    }
    const float mx = sred[0];
    __syncthreads();
    const float ev = __expf(a - mx);
    she[s] = ev;
    shf[s] = ev;
    const int chg = (s == 0) ? 1 : (shtg[s] != shtg[s - 1]);
    shi[s] = chg;
    __syncthreads();
    for (int off = 1; off < 256; off <<= 1) {
        const float fv = (s >= off) ? shf[s - off] : 0.f;
        const int   iv = (s >= off) ? shi[s - off] : 0;
        __syncthreads();
        shf[s] += fv;     // -> ZC[s+1]
        shi[s] += iv;     // -> runid[s]
        __syncthreads();
    }
    // segmented Pw scan (80 lanes, 64-step chains)
    if (s < 80) {
        const int t = s % 20, seg = s / 20;
        const int base = seg * 64;
        float pw = 0.f;
        for (int k = 0; k < 64; k++) {
            pw = fmaf(she[base + k], shw0[(base + k) * 20 + t], pw);
            shpw[(base + k) * 20 + t] = pw;
        }
    }
    __syncthreads();
    if (s < 20) {
        const float T0 = shpw[63 * 20 + s], T1 = shpw[127 * 20 + s], T2 = shpw[191 * 20 + s];
        soff[0][s] = 0.f; soff[1][s] = T0; soff[2][s] = T0 + T1; soff[3][s] = T0 + T1 + T2;
        sPwi[s]  = (i == 0) ? 0.f : shpw[(i - 1) * 20 + s] + soff[(i - 1) >> 6][s];
        shw1i[s] = ws[WS_HW1 + i * 20 + s];
        sfcb[s]  = fcb[s];
    }
    __syncthreads();

    float lossacc = 0.f;
    if (j > i) {
        const float ZCi  = (i == 0) ? 0.f : shf[i - 1];
        const float invz = 1.f / (shf[j] - ZCi);
        const int L = j - i + 1;
        const int sti = (i == 0) ? 1 : (shtg[i] != shtg[i - 1]);
        const int enj = (j == 255) ? 1 : (shtg[j] != shtg[j + 1]);
        const int lbl = (shi[i] == shi[j] && sti && enj) ? shtg[j] : 0;

        const float4* pj4 = (const float4*)&shpw[j * 20];
        const float4* so4 = (const float4*)&soff[j >> 6][0];
        const float4* pi4 = (const float4*)sPwi;
        const float4* h14 = (const float4*)shw1i;
        const float4* h24 = (const float4*)&ws[WS_HW2 + j * 20];
        const float4* lw4 = (const float4*)&ws[WS_LW + L * 20];
        const float4* fb4 = (const float4*)sfcb;
        const int p = i * (511 - i) / 2 + (j - i - 1);
        float4* op4 = (float4*)(out + (size_t)p * 20);

        float lg[20];
        float mxl = -1e30f, chosen = 0.f;
        #pragma unroll
        for (int q = 0; q < 5; q++) {
            const float4 pj = pj4[q], so = so4[q], pi = pi4[q];
            const float4 h1 = h14[q], h2 = h24[q];
            const float4 lw = lw4[q], fb = fb4[q];
            float4 r;
            r.x = (pj.x + so.x - pi.x) * invz + h1.x + h2.x + lw.x + fb.x;
            r.y = (pj.y + so.y - pi.y) * invz + h1.y + h2.y + lw.y + fb.y;
            r.z = (pj.z + so.z - pi.z) * invz + h1.z + h2.z + lw.z + fb.z;
            r.w = (pj.w + so.w - pi.w) * invz + h1.w + h2.w + lw.w + fb.w;
            op4[q] = r;
            lg[q * 4 + 0] = r.x; lg[q * 4 + 1] = r.y;
            lg[q * 4 + 2] = r.z; lg[q * 4 + 3] = r.w;
            mxl = fmaxf(mxl, fmaxf(fmaxf(r.x, r.y), fmaxf(r.z, r.w)));
            chosen = (q * 4 + 0 == lbl) ? r.x : chosen;
            chosen = (q * 4 + 1 == lbl) ? r.y : chosen;
            chosen = (q * 4 + 2 == lbl) ? r.z : chosen;
            chosen = (q * 4 + 3 == lbl) ? r.w : chosen;
        }
        float se = 0.f;
        #pragma unroll
        for (int t = 0; t < 20; t++) se += __expf(lg[t] - mxl);
        lossacc = -(chosen - mxl - __logf(se));
    }
    sred[j] = lossacc;
    __syncthreads();
    for (int off = 128; off > 0; off >>= 1) {
        if (j < off) sred[j] += sred[j + off];
        __syncthreads();
    }
    if (j == 0) ws[WS_LOSSP + i] = sred[0];
}

// ============ K4: final loss reduce over 255 partials ============
__global__ __launch_bounds__(256) void K4(float* __restrict__ out,
                                          float* __restrict__ ws) {
    __shared__ float sh[256];
    const int t = threadIdx.x;
    sh[t] = (t < 255) ? ws[WS_LOSSP + t] : 0.f;
    __syncthreads();
    for (int off = 128; off > 0; off >>= 1) {
        if (t < off) sh[t] += sh[t + off];
        __syncthreads();
    }
    if (t == 0) out[(size_t)NPAIR * 20] = sh[0] / (float)NPAIR;
}

extern "C" void kernel_launch(void* const* d_in, const int* in_sizes, int n_in,
                              void* d_out, int out_size, void* d_ws, size_t ws_size,
                              hipStream_t stream) {
    (void)in_sizes; (void)n_in; (void)out_size; (void)ws_size;
    const float* hidden = (const float*)d_in[0];
    const int*   target = (const int*)d_in[1];
    const float* w1     = (const float*)d_in[2];
    const float* b1     = (const float*)d_in[3];
    const float* w2     = (const float*)d_in[4];
    const float* b2     = (const float*)d_in[5];
    const float* lenemb = (const float*)d_in[6];
    const float* fcw    = (const float*)d_in[7];
    const float* fcb    = (const float*)d_in[8];
    float* out = (float*)d_out;
    float* ws  = (float*)d_ws;

    K1<<<640, 256, 0, stream>>>(hidden, w1, fcw, ws);
    K2<<<256, 256, 0, stream>>>(b1, w2, lenemb, fcw, ws);
    K3<<<255, 256, 0, stream>>>(target, b2, fcb, out, ws);
    K4<<<1, 256, 0, stream>>>(out, ws);
}